// Round 18
// baseline (7308.118 us; speedup 1.0000x reference)
//
#include <hip/hip_runtime.h>

// ---------------------------------------------------------------------------
// PerVarDecoder: 2-layer LSTM (D=512, B=512, L=256) on MI355X.
// R9: 7342. R13: 6839 (y-GEMM hidden). R15: 4180 (2-way K-split). R17: flag
//   barrier (kept). R18: 8 waves, 8-link chain -- 4133us, ~neutral => chain
//   LENGTH no longer the bottleneck; the serialized-ATOMIC link latency is.
//   R16-vs-R18 A/B: toxic ingredient was 4-MFMA/load shape, reduce is fine.
// R19 (this round): Phase-A acquire fence + PLAIN pipelined h loads (the R10
//   pattern, correctly scoped). R10 PASSED this pattern; its regression came
//   from Phase B L2 thrash (wih1p/y0 hot). Phase A's L2 is COLD (W in LDS,
//   h/y0 stores bypass L2) -> per-step buffer_inv is ~free, and the 8-link
//   chain becomes 8 UNORDERED plain loads = ~1 LLC RTT instead of 8 serial.
//   Phase B keeps ld16_dev (protects L2-hot wih1p/y0). Single change on R18.
// ---------------------------------------------------------------------------

typedef __bf16 bf16_t;
typedef __bf16 bf16x8 __attribute__((ext_vector_type(8)));
typedef float f32x4 __attribute__((ext_vector_type(4)));
typedef float f32x16 __attribute__((ext_vector_type(16)));

#define D_ 512
#define NB 256      // total blocks
#define TPB 256     // helper kernels
#define TPBM 512    // main kernel: 8 waves
#define SCOPE_DEV __HIP_MEMORY_SCOPE_AGENT

// ---- workspace layout (bytes) ----
#define OFF_O        0u
#define OFF_CTR      524288u           // flags: 16 groups x 16 blocks x 4B (zeroed 4KB)
#define OFF_HL0      528384u           // 2 * 262144 bf16 = 1048576
#define OFF_HL1      1576960u          // 1048576
#define OFF_CL0      2625536u          // 262144 f32 = 1048576
#define OFF_CL1      3674112u          // 1048576
#define OFF_CSB      4722688u          // 262144 bf16 = 524288
#define OFF_IHWB     5246976u          // 524288 bf16 = 1048576
#define OFF_ICWB     6295552u          // 1048576
#define OFF_WHH0B    7344128u          // 1048576 bf16 = 2097152
#define OFF_WHH1B    9441280u          // 2097152
#define OFF_WIH1P    11538432u         // 2097152
#define OFF_GB0      13635584u         // 2048 f32 = 8192
#define OFF_GB1      13643776u         // 8192
#define OFF_Y0       13651968u         // 256*262144 bf16 = 134217728
#define OFF_OP       147869696u        // 16 * 131072 f32 = 8388608
// total ~156 MB

__device__ __forceinline__ float sigm(float x) { return 1.0f / (1.0f + __expf(-x)); }
__device__ __forceinline__ float tanh_f(float x) { return 1.0f - 2.0f / (__expf(2.0f * x) + 1.0f); }

// 16B device-coherent load (2x 8B relaxed agent atomics -> sc1 bypass to LLC)
__device__ __forceinline__ bf16x8 ld16_dev(const bf16_t* p) {
    const unsigned long long* q = (const unsigned long long*)p;
    unsigned long long v0 = __hip_atomic_load(q, __ATOMIC_RELAXED, SCOPE_DEV);
    unsigned long long v1 = __hip_atomic_load(q + 1, __ATOMIC_RELAXED, SCOPE_DEV);
    union { unsigned long long u[2]; bf16x8 v; } c;
    c.u[0] = v0; c.u[1] = v1;
    return c.v;
}
// 8B device-coherent store (write-through to LLC)
__device__ __forceinline__ void st8_dev(bf16_t* p, unsigned long long v) {
    __hip_atomic_store((unsigned long long*)p, v, __ATOMIC_RELAXED, SCOPE_DEV);
}

// ---------------- prep: fp32->bf16 conversions + bias sums ----------------
__global__ void prep_kernel(const float* __restrict__ c_star, const float* __restrict__ ihw,
                            const float* __restrict__ icw, const float* __restrict__ whh0,
                            const float* __restrict__ whh1, const float* __restrict__ bi0,
                            const float* __restrict__ bh0, const float* __restrict__ bi1,
                            const float* __restrict__ bh1,
                            bf16_t* __restrict__ csb, bf16_t* __restrict__ ihwb,
                            bf16_t* __restrict__ icwb, bf16_t* __restrict__ whh0b,
                            bf16_t* __restrict__ whh1b, float* __restrict__ gb0,
                            float* __restrict__ gb1) {
    int id = blockIdx.x * TPB + threadIdx.x;
    if (id < 262144) { csb[id] = (bf16_t)c_star[id]; return; }
    id -= 262144;
    if (id < 524288) { ihwb[id] = (bf16_t)ihw[id]; return; }
    id -= 524288;
    if (id < 524288) { icwb[id] = (bf16_t)icw[id]; return; }
    id -= 524288;
    if (id < 1048576) { whh0b[id] = (bf16_t)whh0[id]; return; }
    id -= 1048576;
    if (id < 1048576) { whh1b[id] = (bf16_t)whh1[id]; return; }
    id -= 1048576;
    if (id < 2048) { gb0[id] = bi0[id] + bh0[id]; return; }
    id -= 2048;
    if (id < 2048) { gb1[id] = bi1[id] + bh1[id]; return; }
}

// ---------------- pack W_ih1 into MFMA B-fragment order ----------------
__global__ void pack_wih1_kernel(const float* __restrict__ W, bf16_t* __restrict__ out) {
    int id = blockIdx.x * TPB + threadIdx.x;  // 131072 chunks
    int j = id >> 13;
    int ch = id & 8191;
    int c = ch >> 6;             // 0..127 local col
    int k0 = (ch & 63) << 3;     // 0..511 step 8
    int q = c >> 5, dd = c & 31;
    int src = (q * 512 + j * 32 + dd) * 512 + k0;
    int kt = k0 >> 4, hi = (k0 >> 3) & 1;
    int off = (j * 4 + q) * 16384 + kt * 512 + ((hi << 5) + dd) * 8;
#pragma unroll
    for (int jj = 0; jj < 8; jj++) out[off + jj] = (bf16_t)W[src + jj];
}

// ---------------- init GEMM: h0/c0 = tanh(c_star @ W.T + b) ----------------
__global__ __launch_bounds__(TPB) void init_gemm_kernel(
    const bf16_t* __restrict__ csb, const bf16_t* __restrict__ ihwb,
    const bf16_t* __restrict__ icwb, const float* __restrict__ ihb,
    const float* __restrict__ icb, bf16_t* __restrict__ hl0, bf16_t* __restrict__ hl1,
    float* __restrict__ cl0, float* __restrict__ cl1) {
    int bid = blockIdx.x;
    int mt = bid & 15, nt = bid >> 4;
    int tid = threadIdx.x;
    int w = tid >> 6, l = tid & 63;
    int lane32 = l & 31, lhi = l >> 5;
    int m0 = mt * 32;
    int n0 = nt * 128 + w * 32;  // 0..2047
    bool is_h = (n0 < 1024);
    const bf16_t* Bmat = is_h ? ihwb : icwb;
    const float* bias = is_h ? ihb : icb;
    int nloc = is_h ? n0 : (n0 - 1024);

    f32x16 acc = {};
    const bf16_t* ap = csb + (m0 + lane32) * 512 + lhi * 8;
    const bf16_t* bp = Bmat + (nloc + lane32) * 512 + lhi * 8;
#pragma unroll
    for (int kt = 0; kt < 32; kt++) {
        bf16x8 a = *(const bf16x8*)(ap + kt * 16);
        bf16x8 b = *(const bf16x8*)(bp + kt * 16);
        acc = __builtin_amdgcn_mfma_f32_32x32x16_bf16(a, b, acc, 0, 0, 0);
    }
    int n = nloc + lane32;
    float bv = bias[n];
#pragma unroll
    for (int reg = 0; reg < 16; reg++) {
        int row = (reg & 3) + ((reg >> 2) << 3) + (lhi << 2);
        int m = m0 + row;
        float v = tanh_f(acc[reg] + bv);
        int flat = m * 1024 + n;  // reshape(NL,B,D) flat split semantics
        if (is_h) {
            if (flat < 262144) hl0[flat] = (bf16_t)v;
            else hl1[flat - 262144] = (bf16_t)v;
        } else {
            if (flat < 262144) cl0[flat] = v;
            else cl1[flat - 262144] = v;
        }
    }
}

// ---------------- main persistent cooperative LSTM kernel (8 waves) --------
__global__ __launch_bounds__(TPBM, 1) void lstm_main_kernel(
    const bf16_t* __restrict__ whh0, const bf16_t* __restrict__ whh1,
    const bf16_t* __restrict__ wih1p, const float* __restrict__ gb0,
    const float* __restrict__ gb1, const float* __restrict__ out_w,
    bf16_t* __restrict__ hl0, bf16_t* __restrict__ hl1,
    const float* __restrict__ cl0i, const float* __restrict__ cl1i,
    bf16_t* __restrict__ y0, float* __restrict__ OP, unsigned* __restrict__ flg) {
    __shared__ __align__(16) char smem[163840];  // 128KB W frags + 32KB partials
    bf16_t* Wlds = (bf16_t*)smem;
    float* P = (float*)(smem + 131072);  // [2 halves][4 q][32 row][32 col] f32

    const int bid = blockIdx.x;
    const int r8 = bid & 7, k8 = bid >> 3;
    const int g = r8 + ((k8 >> 4) << 3);  // group 0..15 (same-XCD hint)
    const int j = k8 & 15;                // d-slice within group
    const int b0 = g * 32, d0 = j * 32;
    const int tid = threadIdx.x;
    const int w = tid >> 6, l = tid & 63;  // 8 waves
    const int lane32 = l & 31, lhi = l >> 5;
    const int qt = w >> 1;               // K-quarter 0..3 (8 links each)
    const int q0 = (w & 1) << 1;         // quadrant pair base (0 or 2)
    const int prow = tid >> 3, pc4 = (tid & 7) << 2;  // elementwise (tid<256 only)
    unsigned* gflags = flg + g * 16;     // one 64B line per group, 16 dword flags

    // stage W_hh0 into frag-major LDS (input written by prior kernel: plain loads ok)
    for (int ch = tid; ch < 8192; ch += TPBM) {
        int c = ch >> 6, k0 = (ch & 63) << 3;
        int q = c >> 5, dd = c & 31;
        bf16x8 v = *(const bf16x8*)(whh0 + (q * 512 + d0 + dd) * 512 + k0);
        *(bf16x8*)(Wlds + q * 16384 + (k0 >> 4) * 512 + ((((k0 >> 3) & 1) << 5) + dd) * 8) = v;
    }
    __syncthreads();

    // per-thread state (only meaningful for tid<256: the elementwise threads)
    f32x4 cst = {};
    f32x4 bq[4] = {};
    if (tid < 256) {
        cst = *(const f32x4*)(cl0i + (b0 + prow) * 512 + d0 + pc4);
#pragma unroll
        for (int q = 0; q < 4; q++) bq[q] = *(const f32x4*)(gb0 + q * 512 + d0 + pc4);
    }

    int barcnt = 0;

    // ================= Phase A: layer 0 (input is bias-only) =================
    for (int t = 0; t < 256; t++) {
        // Phase A L2 is cold (W in LDS, h/y0 bypass L2): invalidate is ~free,
        // then PLAIN loads see LLC-resident h and PIPELINE (R10-proven pattern).
        __builtin_amdgcn_fence(__ATOMIC_ACQUIRE, "agent");
        const bf16_t* hcur = hl0 + (t & 1) * 262144;
        bf16_t* hnxt = hl0 + ((t + 1) & 1) * 262144;
        f32x16 acc0 = {}, acc1 = {};
        const bf16_t* ap = hcur + (b0 + lane32) * 512 + qt * 128 + lhi * 8;
        const bf16_t* bpA = Wlds + q0 * 16384 + qt * 4096 + l * 8;
        const bf16_t* bpB = bpA + 16384;
#pragma unroll
        for (int kt = 0; kt < 8; kt++) {
            bf16x8 a = *(const bf16x8*)(ap + kt * 16);
            acc0 = __builtin_amdgcn_mfma_f32_32x32x16_bf16(a, *(const bf16x8*)(bpA + kt * 512), acc0, 0, 0, 0);
            acc1 = __builtin_amdgcn_mfma_f32_32x32x16_bf16(a, *(const bf16x8*)(bpB + kt * 512), acc1, 0, 0, 0);
        }
        // two-round partial reduction into 32KB
        if (qt < 2) {
#pragma unroll
            for (int reg = 0; reg < 16; reg++) {
                int row = (reg & 3) + ((reg >> 2) << 3) + (lhi << 2);
                int o = qt * 4096 + q0 * 1024 + row * 32 + lane32;
                P[o] = acc0[reg];
                P[o + 1024] = acc1[reg];
            }
        }
        __syncthreads();
        if (qt >= 2) {
#pragma unroll
            for (int reg = 0; reg < 16; reg++) {
                int row = (reg & 3) + ((reg >> 2) << 3) + (lhi << 2);
                int o = (qt - 2) * 4096 + q0 * 1024 + row * 32 + lane32;
                P[o] += acc0[reg];
                P[o + 1024] += acc1[reg];
            }
        }
        __syncthreads();
        // fused elementwise -> pack -> store (sum the two halves), tid<256
        if (tid < 256) {
            int eo = prow * 32 + pc4;
            f32x4 gI = *(const f32x4*)(P + eo) + *(const f32x4*)(P + 4096 + eo);
            f32x4 gF = *(const f32x4*)(P + 1024 + eo) + *(const f32x4*)(P + 5120 + eo);
            f32x4 gG = *(const f32x4*)(P + 2048 + eo) + *(const f32x4*)(P + 6144 + eo);
            f32x4 gO = *(const f32x4*)(P + 3072 + eo) + *(const f32x4*)(P + 7168 + eo);
            union { bf16_t h[4]; unsigned long long u; } pk;
#pragma unroll
            for (int k = 0; k < 4; k++) {
                float iv = sigm(gI[k] + bq[0][k]);
                float fv = sigm(gF[k] + bq[1][k]);
                float gv = tanh_f(gG[k] + bq[2][k]);
                float ov = sigm(gO[k] + bq[3][k]);
                float cv = fv * cst[k] + iv * gv;
                cst[k] = cv;
                pk.h[k] = (bf16_t)(ov * tanh_f(cv));
            }
            int gi = (b0 + prow) * 512 + d0 + pc4;
            st8_dev(hnxt + gi, pk.u);
            st8_dev(y0 + t * 262144 + gi, pk.u);
        }
        asm volatile("s_waitcnt vmcnt(0)" ::: "memory");
        __syncthreads();
        barcnt++;
        if (tid == 0) __hip_atomic_store(gflags + j, (unsigned)barcnt, __ATOMIC_RELAXED, SCOPE_DEV);
        if (w == 0) {
            const unsigned tgt = (unsigned)barcnt;
            for (;;) {
                unsigned v = tgt;
                if (l < 16) v = __hip_atomic_load(gflags + l, __ATOMIC_RELAXED, SCOPE_DEV);
                if (__all((int)(v >= tgt))) break;
                __builtin_amdgcn_s_sleep(1);
            }
        }
        __syncthreads();
    }

    // stage W_hh1 (all waves past GEMM reads due to final barrier)
    for (int ch = tid; ch < 8192; ch += TPBM) {
        int c = ch >> 6, k0 = (ch & 63) << 3;
        int q = c >> 5, dd = c & 31;
        bf16x8 v = *(const bf16x8*)(whh1 + (q * 512 + d0 + dd) * 512 + k0);
        *(bf16x8*)(Wlds + q * 16384 + (k0 >> 4) * 512 + ((((k0 >> 3) & 1) << 5) + dd) * 8) = v;
    }
    __syncthreads();
    f32x4 own = {};
    if (tid < 256) {
        cst = *(const f32x4*)(cl1i + (b0 + prow) * 512 + d0 + pc4);
#pragma unroll
        for (int q = 0; q < 4; q++) bq[q] = *(const f32x4*)(gb1 + q * 512 + d0 + pc4);
        own = *(const f32x4*)(out_w + d0 + pc4);
    }
    // W_ih1 fragment bases: this wave's quadrant pair + K-quarter
    const bf16_t* wpA = wih1p + (j * 4 + q0) * 16384 + qt * 4096 + l * 8;
    const bf16_t* wpB = wpA + 16384;
    float* opj = OP + j * 131072;  // this block's private O-partial slice

    // prologue: y-GEMM for t=0 (y0 immutable since Phase A; plain cached loads)
    f32x16 yacc0 = {}, yacc1 = {};
    {
        const bf16_t* yp = y0 + (b0 + lane32) * 512 + qt * 128 + lhi * 8;
#pragma unroll
        for (int kt = 0; kt < 8; kt++) {
            bf16x8 a = *(const bf16x8*)(yp + kt * 16);
            yacc0 = __builtin_amdgcn_mfma_f32_32x32x16_bf16(a, *(const bf16x8*)(wpA + kt * 512), yacc0, 0, 0, 0);
            yacc1 = __builtin_amdgcn_mfma_f32_32x32x16_bf16(a, *(const bf16x8*)(wpB + kt * 512), yacc1, 0, 0, 0);
        }
    }

    // ================= Phase B: layer 1 (K=1024 fused) + out proj ============
    for (int t = 0; t < 256; t++) {
        const bf16_t* hcur = hl1 + (t & 1) * 262144;
        bf16_t* hnxt = hl1 + ((t + 1) & 1) * 262144;
        f32x16 acc0 = yacc0, acc1 = yacc1;  // y contribution (hidden under prev wait)
        {
            const bf16_t* ap = hcur + (b0 + lane32) * 512 + qt * 128 + lhi * 8;
            const bf16_t* bpA = Wlds + q0 * 16384 + qt * 4096 + l * 8;
            const bf16_t* bpB = bpA + 16384;
#pragma unroll
            for (int kt = 0; kt < 8; kt++) {
                bf16x8 a = ld16_dev(ap + kt * 16);
                acc0 = __builtin_amdgcn_mfma_f32_32x32x16_bf16(a, *(const bf16x8*)(bpA + kt * 512), acc0, 0, 0, 0);
                acc1 = __builtin_amdgcn_mfma_f32_32x32x16_bf16(a, *(const bf16x8*)(bpB + kt * 512), acc1, 0, 0, 0);
            }
        }
        if (qt < 2) {
#pragma unroll
            for (int reg = 0; reg < 16; reg++) {
                int row = (reg & 3) + ((reg >> 2) << 3) + (lhi << 2);
                int o = qt * 4096 + q0 * 1024 + row * 32 + lane32;
                P[o] = acc0[reg];
                P[o + 1024] = acc1[reg];
            }
        }
        __syncthreads();
        if (qt >= 2) {
#pragma unroll
            for (int reg = 0; reg < 16; reg++) {
                int row = (reg & 3) + ((reg >> 2) << 3) + (lhi << 2);
                int o = (qt - 2) * 4096 + q0 * 1024 + row * 32 + lane32;
                P[o] += acc0[reg];
                P[o + 1024] += acc1[reg];
            }
        }
        __syncthreads();
        // fused elementwise -> pack -> store + out-proj partial, tid<256
        if (tid < 256) {
            int eo = prow * 32 + pc4;
            f32x4 gI = *(const f32x4*)(P + eo) + *(const f32x4*)(P + 4096 + eo);
            f32x4 gF = *(const f32x4*)(P + 1024 + eo) + *(const f32x4*)(P + 5120 + eo);
            f32x4 gG = *(const f32x4*)(P + 2048 + eo) + *(const f32x4*)(P + 6144 + eo);
            f32x4 gO = *(const f32x4*)(P + 3072 + eo) + *(const f32x4*)(P + 7168 + eo);
            union { bf16_t h[4]; unsigned long long u; } pk;
            float part = 0.0f;
#pragma unroll
            for (int k = 0; k < 4; k++) {
                float iv = sigm(gI[k] + bq[0][k]);
                float fv = sigm(gF[k] + bq[1][k]);
                float gv = tanh_f(gG[k] + bq[2][k]);
                float ov = sigm(gO[k] + bq[3][k]);
                float cv = fv * cst[k] + iv * gv;
                cst[k] = cv;
                float hv = ov * tanh_f(cv);
                pk.h[k] = (bf16_t)hv;
                part += hv * own[k];
            }
#pragma unroll
            for (int off = 1; off < 8; off <<= 1) part += __shfl_xor(part, off, 8);
            if ((tid & 7) == 0) opj[t * 512 + b0 + prow] = part;
            st8_dev(hnxt + (b0 + prow) * 512 + d0 + pc4, pk.u);
        }
        asm volatile("s_waitcnt vmcnt(0)" ::: "memory");
        __syncthreads();
        barcnt++;
        if (tid == 0) __hip_atomic_store(gflags + j, (unsigned)barcnt, __ATOMIC_RELAXED, SCOPE_DEV);
        // overlap: next step's y-GEMM (independent, immutable y0) hides the wait
        if (t < 255) {
            f32x16 yn0 = {}, yn1 = {};
            const bf16_t* yp = y0 + (t + 1) * 262144 + (b0 + lane32) * 512 + qt * 128 + lhi * 8;
#pragma unroll
            for (int kt = 0; kt < 8; kt++) {
                bf16x8 a = *(const bf16x8*)(yp + kt * 16);
                yn0 = __builtin_amdgcn_mfma_f32_32x32x16_bf16(a, *(const bf16x8*)(wpA + kt * 512), yn0, 0, 0, 0);
                yn1 = __builtin_amdgcn_mfma_f32_32x32x16_bf16(a, *(const bf16x8*)(wpB + kt * 512), yn1, 0, 0, 0);
            }
            yacc0 = yn0; yacc1 = yn1;
        }
        if (w == 0) {
            const unsigned tgt = (unsigned)barcnt;
            for (;;) {
                unsigned v = tgt;
                if (l < 16) v = __hip_atomic_load(gflags + l, __ATOMIC_RELAXED, SCOPE_DEV);
                if (__all((int)(v >= tgt))) break;
                __builtin_amdgcn_s_sleep(1);
            }
        }
        __syncthreads();
    }
}

// ------------- finalize: 16-way O-partial reduce + out_b + reorder -------------
__global__ void finalize_kernel(const float* __restrict__ OP, const float* __restrict__ out_b,
                                float* __restrict__ out) {
    int id = blockIdx.x * TPB + threadIdx.x;  // 131072
    int t = id >> 9, b = id & 511;
    float v = out_b[0];
#pragma unroll
    for (int jj = 0; jj < 16; jj++) v += OP[jj * 131072 + id];
    if (t < 255) out[b * 255 + t] = v;
    else out[130560 + b] = v;
}

extern "C" void kernel_launch(void* const* d_in, const int* in_sizes, int n_in,
                              void* d_out, int out_size, void* d_ws, size_t ws_size,
                              hipStream_t stream) {
    const float* c_star = (const float*)d_in[0];
    const float* init_h_w = (const float*)d_in[1];
    const float* init_h_b = (const float*)d_in[2];
    const float* init_c_w = (const float*)d_in[3];
    const float* init_c_b = (const float*)d_in[4];
    // d_in[5] = W_ih0 (unused by reference)
    const float* W_hh0 = (const float*)d_in[6];
    const float* b_ih0 = (const float*)d_in[7];
    const float* b_hh0 = (const float*)d_in[8];
    const float* W_ih1 = (const float*)d_in[9];
    const float* W_hh1 = (const float*)d_in[10];
    const float* b_ih1 = (const float*)d_in[11];
    const float* b_hh1 = (const float*)d_in[12];
    const float* out_w = (const float*)d_in[13];
    const float* out_b = (const float*)d_in[14];

    char* ws = (char*)d_ws;
    unsigned* flg = (unsigned*)(ws + OFF_CTR);
    bf16_t* hl0 = (bf16_t*)(ws + OFF_HL0);
    bf16_t* hl1 = (bf16_t*)(ws + OFF_HL1);
    float* cl0 = (float*)(ws + OFF_CL0);
    float* cl1 = (float*)(ws + OFF_CL1);
    bf16_t* csb = (bf16_t*)(ws + OFF_CSB);
    bf16_t* ihwb = (bf16_t*)(ws + OFF_IHWB);
    bf16_t* icwb = (bf16_t*)(ws + OFF_ICWB);
    bf16_t* whh0b = (bf16_t*)(ws + OFF_WHH0B);
    bf16_t* whh1b = (bf16_t*)(ws + OFF_WHH1B);
    bf16_t* wih1p = (bf16_t*)(ws + OFF_WIH1P);
    float* gb0 = (float*)(ws + OFF_GB0);
    float* gb1 = (float*)(ws + OFF_GB1);
    bf16_t* y0 = (bf16_t*)(ws + OFF_Y0);
    float* OP = (float*)(ws + OFF_OP);

    // zero barrier flags (ws is poisoned each call); OP fully overwritten before read
    hipMemsetAsync(ws + OFF_CTR, 0, 4096, stream);

    prep_kernel<<<13328, TPB, 0, stream>>>(c_star, init_h_w, init_c_w, W_hh0, W_hh1,
                                           b_ih0, b_hh0, b_ih1, b_hh1,
                                           csb, ihwb, icwb, whh0b, whh1b, gb0, gb1);
    pack_wih1_kernel<<<512, TPB, 0, stream>>>(W_ih1, wih1p);
    init_gemm_kernel<<<256, TPB, 0, stream>>>(csb, ihwb, icwb, init_h_b, init_c_b,
                                              hl0, hl1, cl0, cl1);

    const bf16_t* a_whh0 = whh0b; const bf16_t* a_whh1 = whh1b;
    const bf16_t* a_wih1p = wih1p; const float* a_gb0 = gb0; const float* a_gb1 = gb1;
    const float* a_outw = out_w;
    bf16_t* a_hl0 = hl0; bf16_t* a_hl1 = hl1;
    const float* a_cl0 = cl0; const float* a_cl1 = cl1;
    bf16_t* a_y0 = y0; float* a_OP = OP; unsigned* a_flg = flg;
    void* args[] = {&a_whh0, &a_whh1, &a_wih1p, &a_gb0, &a_gb1, &a_outw,
                    &a_hl0, &a_hl1, &a_cl0, &a_cl1, &a_y0, &a_OP, &a_flg};
    hipLaunchCooperativeKernel((void*)lstm_main_kernel, dim3(NB), dim3(TPBM), args, 0, stream);

    finalize_kernel<<<512, TPB, 0, stream>>>(OP, out_b, (float*)d_out);
}

// Round 19
// 4126.191 us; speedup vs baseline: 1.7712x; 1.7712x over previous
//
#include <hip/hip_runtime.h>

// ---------------------------------------------------------------------------
// PerVarDecoder: 2-layer LSTM (D=512, B=512, L=256) on MI355X.
// Session ladder: 9394 (R0 baseline) -> 7982 (R2: padded ctrs, OP partials)
//   -> 7342 (R9: plain cached y/W_ih1 loads) -> 6839 (R13: y-GEMM hidden
//   under barrier wait) -> 4180 (R15: 2-way K-split of coherent h chain)
//   -> 4133 (R17 flag barrier + R18 8-wave 8-link chain).
// Closed paths (verified): batched/pipelined COHERENT h-loads (5x identical
//   0.2495 failures: R3/R5/R8/R11/R16); acquire-fence + plain h-loads (R10,
//   R19: fence costs >> savings); layer merge (R12: L2 thrash); 4-MFMA/load
//   shape (R16 vs R18 A/B: the toxic ingredient).
// R20 (final): byte-identical resubmit of R18 -- the best verified kernel.
//   Structure: persistent coop kernel, 16 groups x 16 d-slices; 8 waves/block,
//   wave = (K-quarter, quadrant-pair), 8-link serialized coherent chain with
//   1 ld16_dev -> 2 MFMAs (LDS B); two-round LDS partial reduce; fused
//   elementwise->pack->st8_dev; flag-array group barrier; Phase-B y-GEMM(t+1)
//   computed between barrier arrive and poll.
// ---------------------------------------------------------------------------

typedef __bf16 bf16_t;
typedef __bf16 bf16x8 __attribute__((ext_vector_type(8)));
typedef float f32x4 __attribute__((ext_vector_type(4)));
typedef float f32x16 __attribute__((ext_vector_type(16)));

#define D_ 512
#define NB 256      // total blocks
#define TPB 256     // helper kernels
#define TPBM 512    // main kernel: 8 waves
#define SCOPE_DEV __HIP_MEMORY_SCOPE_AGENT

// ---- workspace layout (bytes) ----
#define OFF_O        0u
#define OFF_CTR      524288u           // flags: 16 groups x 16 blocks x 4B (zeroed 4KB)
#define OFF_HL0      528384u           // 2 * 262144 bf16 = 1048576
#define OFF_HL1      1576960u          // 1048576
#define OFF_CL0      2625536u          // 262144 f32 = 1048576
#define OFF_CL1      3674112u          // 1048576
#define OFF_CSB      4722688u          // 262144 bf16 = 524288
#define OFF_IHWB     5246976u          // 524288 bf16 = 1048576
#define OFF_ICWB     6295552u          // 1048576
#define OFF_WHH0B    7344128u          // 1048576 bf16 = 2097152
#define OFF_WHH1B    9441280u          // 2097152
#define OFF_WIH1P    11538432u         // 2097152
#define OFF_GB0      13635584u         // 2048 f32 = 8192
#define OFF_GB1      13643776u         // 8192
#define OFF_Y0       13651968u         // 256*262144 bf16 = 134217728
#define OFF_OP       147869696u        // 16 * 131072 f32 = 8388608
// total ~156 MB

__device__ __forceinline__ float sigm(float x) { return 1.0f / (1.0f + __expf(-x)); }
__device__ __forceinline__ float tanh_f(float x) { return 1.0f - 2.0f / (__expf(2.0f * x) + 1.0f); }

// 16B device-coherent load (2x 8B relaxed agent atomics -> sc1 bypass to LLC)
__device__ __forceinline__ bf16x8 ld16_dev(const bf16_t* p) {
    const unsigned long long* q = (const unsigned long long*)p;
    unsigned long long v0 = __hip_atomic_load(q, __ATOMIC_RELAXED, SCOPE_DEV);
    unsigned long long v1 = __hip_atomic_load(q + 1, __ATOMIC_RELAXED, SCOPE_DEV);
    union { unsigned long long u[2]; bf16x8 v; } c;
    c.u[0] = v0; c.u[1] = v1;
    return c.v;
}
// 8B device-coherent store (write-through to LLC)
__device__ __forceinline__ void st8_dev(bf16_t* p, unsigned long long v) {
    __hip_atomic_store((unsigned long long*)p, v, __ATOMIC_RELAXED, SCOPE_DEV);
}

// ---------------- prep: fp32->bf16 conversions + bias sums ----------------
__global__ void prep_kernel(const float* __restrict__ c_star, const float* __restrict__ ihw,
                            const float* __restrict__ icw, const float* __restrict__ whh0,
                            const float* __restrict__ whh1, const float* __restrict__ bi0,
                            const float* __restrict__ bh0, const float* __restrict__ bi1,
                            const float* __restrict__ bh1,
                            bf16_t* __restrict__ csb, bf16_t* __restrict__ ihwb,
                            bf16_t* __restrict__ icwb, bf16_t* __restrict__ whh0b,
                            bf16_t* __restrict__ whh1b, float* __restrict__ gb0,
                            float* __restrict__ gb1) {
    int id = blockIdx.x * TPB + threadIdx.x;
    if (id < 262144) { csb[id] = (bf16_t)c_star[id]; return; }
    id -= 262144;
    if (id < 524288) { ihwb[id] = (bf16_t)ihw[id]; return; }
    id -= 524288;
    if (id < 524288) { icwb[id] = (bf16_t)icw[id]; return; }
    id -= 524288;
    if (id < 1048576) { whh0b[id] = (bf16_t)whh0[id]; return; }
    id -= 1048576;
    if (id < 1048576) { whh1b[id] = (bf16_t)whh1[id]; return; }
    id -= 1048576;
    if (id < 2048) { gb0[id] = bi0[id] + bh0[id]; return; }
    id -= 2048;
    if (id < 2048) { gb1[id] = bi1[id] + bh1[id]; return; }
}

// ---------------- pack W_ih1 into MFMA B-fragment order ----------------
__global__ void pack_wih1_kernel(const float* __restrict__ W, bf16_t* __restrict__ out) {
    int id = blockIdx.x * TPB + threadIdx.x;  // 131072 chunks
    int j = id >> 13;
    int ch = id & 8191;
    int c = ch >> 6;             // 0..127 local col
    int k0 = (ch & 63) << 3;     // 0..511 step 8
    int q = c >> 5, dd = c & 31;
    int src = (q * 512 + j * 32 + dd) * 512 + k0;
    int kt = k0 >> 4, hi = (k0 >> 3) & 1;
    int off = (j * 4 + q) * 16384 + kt * 512 + ((hi << 5) + dd) * 8;
#pragma unroll
    for (int jj = 0; jj < 8; jj++) out[off + jj] = (bf16_t)W[src + jj];
}

// ---------------- init GEMM: h0/c0 = tanh(c_star @ W.T + b) ----------------
__global__ __launch_bounds__(TPB) void init_gemm_kernel(
    const bf16_t* __restrict__ csb, const bf16_t* __restrict__ ihwb,
    const bf16_t* __restrict__ icwb, const float* __restrict__ ihb,
    const float* __restrict__ icb, bf16_t* __restrict__ hl0, bf16_t* __restrict__ hl1,
    float* __restrict__ cl0, float* __restrict__ cl1) {
    int bid = blockIdx.x;
    int mt = bid & 15, nt = bid >> 4;
    int tid = threadIdx.x;
    int w = tid >> 6, l = tid & 63;
    int lane32 = l & 31, lhi = l >> 5;
    int m0 = mt * 32;
    int n0 = nt * 128 + w * 32;  // 0..2047
    bool is_h = (n0 < 1024);
    const bf16_t* Bmat = is_h ? ihwb : icwb;
    const float* bias = is_h ? ihb : icb;
    int nloc = is_h ? n0 : (n0 - 1024);

    f32x16 acc = {};
    const bf16_t* ap = csb + (m0 + lane32) * 512 + lhi * 8;
    const bf16_t* bp = Bmat + (nloc + lane32) * 512 + lhi * 8;
#pragma unroll
    for (int kt = 0; kt < 32; kt++) {
        bf16x8 a = *(const bf16x8*)(ap + kt * 16);
        bf16x8 b = *(const bf16x8*)(bp + kt * 16);
        acc = __builtin_amdgcn_mfma_f32_32x32x16_bf16(a, b, acc, 0, 0, 0);
    }
    int n = nloc + lane32;
    float bv = bias[n];
#pragma unroll
    for (int reg = 0; reg < 16; reg++) {
        int row = (reg & 3) + ((reg >> 2) << 3) + (lhi << 2);
        int m = m0 + row;
        float v = tanh_f(acc[reg] + bv);
        int flat = m * 1024 + n;  // reshape(NL,B,D) flat split semantics
        if (is_h) {
            if (flat < 262144) hl0[flat] = (bf16_t)v;
            else hl1[flat - 262144] = (bf16_t)v;
        } else {
            if (flat < 262144) cl0[flat] = v;
            else cl1[flat - 262144] = v;
        }
    }
}

// ---------------- main persistent cooperative LSTM kernel (8 waves) --------
__global__ __launch_bounds__(TPBM, 1) void lstm_main_kernel(
    const bf16_t* __restrict__ whh0, const bf16_t* __restrict__ whh1,
    const bf16_t* __restrict__ wih1p, const float* __restrict__ gb0,
    const float* __restrict__ gb1, const float* __restrict__ out_w,
    bf16_t* __restrict__ hl0, bf16_t* __restrict__ hl1,
    const float* __restrict__ cl0i, const float* __restrict__ cl1i,
    bf16_t* __restrict__ y0, float* __restrict__ OP, unsigned* __restrict__ flg) {
    __shared__ __align__(16) char smem[163840];  // 128KB W frags + 32KB partials
    bf16_t* Wlds = (bf16_t*)smem;
    float* P = (float*)(smem + 131072);  // [2 halves][4 q][32 row][32 col] f32

    const int bid = blockIdx.x;
    const int r8 = bid & 7, k8 = bid >> 3;
    const int g = r8 + ((k8 >> 4) << 3);  // group 0..15 (same-XCD hint)
    const int j = k8 & 15;                // d-slice within group
    const int b0 = g * 32, d0 = j * 32;
    const int tid = threadIdx.x;
    const int w = tid >> 6, l = tid & 63;  // 8 waves
    const int lane32 = l & 31, lhi = l >> 5;
    const int qt = w >> 1;               // K-quarter 0..3 (8 links each)
    const int q0 = (w & 1) << 1;         // quadrant pair base (0 or 2)
    const int prow = tid >> 3, pc4 = (tid & 7) << 2;  // elementwise (tid<256 only)
    unsigned* gflags = flg + g * 16;     // one 64B line per group, 16 dword flags

    // stage W_hh0 into frag-major LDS (input written by prior kernel: plain loads ok)
    for (int ch = tid; ch < 8192; ch += TPBM) {
        int c = ch >> 6, k0 = (ch & 63) << 3;
        int q = c >> 5, dd = c & 31;
        bf16x8 v = *(const bf16x8*)(whh0 + (q * 512 + d0 + dd) * 512 + k0);
        *(bf16x8*)(Wlds + q * 16384 + (k0 >> 4) * 512 + ((((k0 >> 3) & 1) << 5) + dd) * 8) = v;
    }
    __syncthreads();

    // per-thread state (only meaningful for tid<256: the elementwise threads)
    f32x4 cst = {};
    f32x4 bq[4] = {};
    if (tid < 256) {
        cst = *(const f32x4*)(cl0i + (b0 + prow) * 512 + d0 + pc4);
#pragma unroll
        for (int q = 0; q < 4; q++) bq[q] = *(const f32x4*)(gb0 + q * 512 + d0 + pc4);
    }

    int barcnt = 0;

    // ================= Phase A: layer 0 (input is bias-only) =================
    for (int t = 0; t < 256; t++) {
        const bf16_t* hcur = hl0 + (t & 1) * 262144;
        bf16_t* hnxt = hl0 + ((t + 1) & 1) * 262144;
        f32x16 acc0 = {}, acc1 = {};
        const bf16_t* ap = hcur + (b0 + lane32) * 512 + qt * 128 + lhi * 8;
        const bf16_t* bpA = Wlds + q0 * 16384 + qt * 4096 + l * 8;
        const bf16_t* bpB = bpA + 16384;
#pragma unroll
        for (int kt = 0; kt < 8; kt++) {
            bf16x8 a = ld16_dev(ap + kt * 16);
            acc0 = __builtin_amdgcn_mfma_f32_32x32x16_bf16(a, *(const bf16x8*)(bpA + kt * 512), acc0, 0, 0, 0);
            acc1 = __builtin_amdgcn_mfma_f32_32x32x16_bf16(a, *(const bf16x8*)(bpB + kt * 512), acc1, 0, 0, 0);
        }
        // two-round partial reduction into 32KB
        if (qt < 2) {
#pragma unroll
            for (int reg = 0; reg < 16; reg++) {
                int row = (reg & 3) + ((reg >> 2) << 3) + (lhi << 2);
                int o = qt * 4096 + q0 * 1024 + row * 32 + lane32;
                P[o] = acc0[reg];
                P[o + 1024] = acc1[reg];
            }
        }
        __syncthreads();
        if (qt >= 2) {
#pragma unroll
            for (int reg = 0; reg < 16; reg++) {
                int row = (reg & 3) + ((reg >> 2) << 3) + (lhi << 2);
                int o = (qt - 2) * 4096 + q0 * 1024 + row * 32 + lane32;
                P[o] += acc0[reg];
                P[o + 1024] += acc1[reg];
            }
        }
        __syncthreads();
        // fused elementwise -> pack -> store (sum the two halves), tid<256
        if (tid < 256) {
            int eo = prow * 32 + pc4;
            f32x4 gI = *(const f32x4*)(P + eo) + *(const f32x4*)(P + 4096 + eo);
            f32x4 gF = *(const f32x4*)(P + 1024 + eo) + *(const f32x4*)(P + 5120 + eo);
            f32x4 gG = *(const f32x4*)(P + 2048 + eo) + *(const f32x4*)(P + 6144 + eo);
            f32x4 gO = *(const f32x4*)(P + 3072 + eo) + *(const f32x4*)(P + 7168 + eo);
            union { bf16_t h[4]; unsigned long long u; } pk;
#pragma unroll
            for (int k = 0; k < 4; k++) {
                float iv = sigm(gI[k] + bq[0][k]);
                float fv = sigm(gF[k] + bq[1][k]);
                float gv = tanh_f(gG[k] + bq[2][k]);
                float ov = sigm(gO[k] + bq[3][k]);
                float cv = fv * cst[k] + iv * gv;
                cst[k] = cv;
                pk.h[k] = (bf16_t)(ov * tanh_f(cv));
            }
            int gi = (b0 + prow) * 512 + d0 + pc4;
            st8_dev(hnxt + gi, pk.u);
            st8_dev(y0 + t * 262144 + gi, pk.u);
        }
        asm volatile("s_waitcnt vmcnt(0)" ::: "memory");
        __syncthreads();
        barcnt++;
        if (tid == 0) __hip_atomic_store(gflags + j, (unsigned)barcnt, __ATOMIC_RELAXED, SCOPE_DEV);
        if (w == 0) {
            const unsigned tgt = (unsigned)barcnt;
            for (;;) {
                unsigned v = tgt;
                if (l < 16) v = __hip_atomic_load(gflags + l, __ATOMIC_RELAXED, SCOPE_DEV);
                if (__all((int)(v >= tgt))) break;
                __builtin_amdgcn_s_sleep(1);
            }
        }
        __syncthreads();
    }

    // stage W_hh1 (all waves past GEMM reads due to final barrier)
    for (int ch = tid; ch < 8192; ch += TPBM) {
        int c = ch >> 6, k0 = (ch & 63) << 3;
        int q = c >> 5, dd = c & 31;
        bf16x8 v = *(const bf16x8*)(whh1 + (q * 512 + d0 + dd) * 512 + k0);
        *(bf16x8*)(Wlds + q * 16384 + (k0 >> 4) * 512 + ((((k0 >> 3) & 1) << 5) + dd) * 8) = v;
    }
    __syncthreads();
    f32x4 own = {};
    if (tid < 256) {
        cst = *(const f32x4*)(cl1i + (b0 + prow) * 512 + d0 + pc4);
#pragma unroll
        for (int q = 0; q < 4; q++) bq[q] = *(const f32x4*)(gb1 + q * 512 + d0 + pc4);
        own = *(const f32x4*)(out_w + d0 + pc4);
    }
    // W_ih1 fragment bases: this wave's quadrant pair + K-quarter
    const bf16_t* wpA = wih1p + (j * 4 + q0) * 16384 + qt * 4096 + l * 8;
    const bf16_t* wpB = wpA + 16384;
    float* opj = OP + j * 131072;  // this block's private O-partial slice

    // prologue: y-GEMM for t=0 (y0 immutable since Phase A; plain cached loads)
    f32x16 yacc0 = {}, yacc1 = {};
    {
        const bf16_t* yp = y0 + (b0 + lane32) * 512 + qt * 128 + lhi * 8;
#pragma unroll
        for (int kt = 0; kt < 8; kt++) {
            bf16x8 a = *(const bf16x8*)(yp + kt * 16);
            yacc0 = __builtin_amdgcn_mfma_f32_32x32x16_bf16(a, *(const bf16x8*)(wpA + kt * 512), yacc0, 0, 0, 0);
            yacc1 = __builtin_amdgcn_mfma_f32_32x32x16_bf16(a, *(const bf16x8*)(wpB + kt * 512), yacc1, 0, 0, 0);
        }
    }

    // ================= Phase B: layer 1 (K=1024 fused) + out proj ============
    for (int t = 0; t < 256; t++) {
        const bf16_t* hcur = hl1 + (t & 1) * 262144;
        bf16_t* hnxt = hl1 + ((t + 1) & 1) * 262144;
        f32x16 acc0 = yacc0, acc1 = yacc1;  // y contribution (hidden under prev wait)
        {
            const bf16_t* ap = hcur + (b0 + lane32) * 512 + qt * 128 + lhi * 8;
            const bf16_t* bpA = Wlds + q0 * 16384 + qt * 4096 + l * 8;
            const bf16_t* bpB = bpA + 16384;
#pragma unroll
            for (int kt = 0; kt < 8; kt++) {
                bf16x8 a = ld16_dev(ap + kt * 16);
                acc0 = __builtin_amdgcn_mfma_f32_32x32x16_bf16(a, *(const bf16x8*)(bpA + kt * 512), acc0, 0, 0, 0);
                acc1 = __builtin_amdgcn_mfma_f32_32x32x16_bf16(a, *(const bf16x8*)(bpB + kt * 512), acc1, 0, 0, 0);
            }
        }
        if (qt < 2) {
#pragma unroll
            for (int reg = 0; reg < 16; reg++) {
                int row = (reg & 3) + ((reg >> 2) << 3) + (lhi << 2);
                int o = qt * 4096 + q0 * 1024 + row * 32 + lane32;
                P[o] = acc0[reg];
                P[o + 1024] = acc1[reg];
            }
        }
        __syncthreads();
        if (qt >= 2) {
#pragma unroll
            for (int reg = 0; reg < 16; reg++) {
                int row = (reg & 3) + ((reg >> 2) << 3) + (lhi << 2);
                int o = (qt - 2) * 4096 + q0 * 1024 + row * 32 + lane32;
                P[o] += acc0[reg];
                P[o + 1024] += acc1[reg];
            }
        }
        __syncthreads();
        // fused elementwise -> pack -> store + out-proj partial, tid<256
        if (tid < 256) {
            int eo = prow * 32 + pc4;
            f32x4 gI = *(const f32x4*)(P + eo) + *(const f32x4*)(P + 4096 + eo);
            f32x4 gF = *(const f32x4*)(P + 1024 + eo) + *(const f32x4*)(P + 5120 + eo);
            f32x4 gG = *(const f32x4*)(P + 2048 + eo) + *(const f32x4*)(P + 6144 + eo);
            f32x4 gO = *(const f32x4*)(P + 3072 + eo) + *(const f32x4*)(P + 7168 + eo);
            union { bf16_t h[4]; unsigned long long u; } pk;
            float part = 0.0f;
#pragma unroll
            for (int k = 0; k < 4; k++) {
                float iv = sigm(gI[k] + bq[0][k]);
                float fv = sigm(gF[k] + bq[1][k]);
                float gv = tanh_f(gG[k] + bq[2][k]);
                float ov = sigm(gO[k] + bq[3][k]);
                float cv = fv * cst[k] + iv * gv;
                cst[k] = cv;
                float hv = ov * tanh_f(cv);
                pk.h[k] = (bf16_t)hv;
                part += hv * own[k];
            }
#pragma unroll
            for (int off = 1; off < 8; off <<= 1) part += __shfl_xor(part, off, 8);
            if ((tid & 7) == 0) opj[t * 512 + b0 + prow] = part;
            st8_dev(hnxt + (b0 + prow) * 512 + d0 + pc4, pk.u);
        }
        asm volatile("s_waitcnt vmcnt(0)" ::: "memory");
        __syncthreads();
        barcnt++;
        if (tid == 0) __hip_atomic_store(gflags + j, (unsigned)barcnt, __ATOMIC_RELAXED, SCOPE_DEV);
        // overlap: next step's y-GEMM (independent, immutable y0) hides the wait
        if (t < 255) {
            f32x16 yn0 = {}, yn1 = {};
            const bf16_t* yp = y0 + (t + 1) * 262144 + (b0 + lane32) * 512 + qt * 128 + lhi * 8;
#pragma unroll
            for (int kt = 0; kt < 8; kt++) {
                bf16x8 a = *(const bf16x8*)(yp + kt * 16);
                yn0 = __builtin_amdgcn_mfma_f32_32x32x16_bf16(a, *(const bf16x8*)(wpA + kt * 512), yn0, 0, 0, 0);
                yn1 = __builtin_amdgcn_mfma_f32_32x32x16_bf16(a, *(const bf16x8*)(wpB + kt * 512), yn1, 0, 0, 0);
            }
            yacc0 = yn0; yacc1 = yn1;
        }
        if (w == 0) {
            const unsigned tgt = (unsigned)barcnt;
            for (;;) {
                unsigned v = tgt;
                if (l < 16) v = __hip_atomic_load(gflags + l, __ATOMIC_RELAXED, SCOPE_DEV);
                if (__all((int)(v >= tgt))) break;
                __builtin_amdgcn_s_sleep(1);
            }
        }
        __syncthreads();
    }
}

// ------------- finalize: 16-way O-partial reduce + out_b + reorder -------------
__global__ void finalize_kernel(const float* __restrict__ OP, const float* __restrict__ out_b,
                                float* __restrict__ out) {
    int id = blockIdx.x * TPB + threadIdx.x;  // 131072
    int t = id >> 9, b = id & 511;
    float v = out_b[0];
#pragma unroll
    for (int jj = 0; jj < 16; jj++) v += OP[jj * 131072 + id];
    if (t < 255) out[b * 255 + t] = v;
    else out[130560 + b] = v;
}

extern "C" void kernel_launch(void* const* d_in, const int* in_sizes, int n_in,
                              void* d_out, int out_size, void* d_ws, size_t ws_size,
                              hipStream_t stream) {
    const float* c_star = (const float*)d_in[0];
    const float* init_h_w = (const float*)d_in[1];
    const float* init_h_b = (const float*)d_in[2];
    const float* init_c_w = (const float*)d_in[3];
    const float* init_c_b = (const float*)d_in[4];
    // d_in[5] = W_ih0 (unused by reference)
    const float* W_hh0 = (const float*)d_in[6];
    const float* b_ih0 = (const float*)d_in[7];
    const float* b_hh0 = (const float*)d_in[8];
    const float* W_ih1 = (const float*)d_in[9];
    const float* W_hh1 = (const float*)d_in[10];
    const float* b_ih1 = (const float*)d_in[11];
    const float* b_hh1 = (const float*)d_in[12];
    const float* out_w = (const float*)d_in[13];
    const float* out_b = (const float*)d_in[14];

    char* ws = (char*)d_ws;
    unsigned* flg = (unsigned*)(ws + OFF_CTR);
    bf16_t* hl0 = (bf16_t*)(ws + OFF_HL0);
    bf16_t* hl1 = (bf16_t*)(ws + OFF_HL1);
    float* cl0 = (float*)(ws + OFF_CL0);
    float* cl1 = (float*)(ws + OFF_CL1);
    bf16_t* csb = (bf16_t*)(ws + OFF_CSB);
    bf16_t* ihwb = (bf16_t*)(ws + OFF_IHWB);
    bf16_t* icwb = (bf16_t*)(ws + OFF_ICWB);
    bf16_t* whh0b = (bf16_t*)(ws + OFF_WHH0B);
    bf16_t* whh1b = (bf16_t*)(ws + OFF_WHH1B);
    bf16_t* wih1p = (bf16_t*)(ws + OFF_WIH1P);
    float* gb0 = (float*)(ws + OFF_GB0);
    float* gb1 = (float*)(ws + OFF_GB1);
    bf16_t* y0 = (bf16_t*)(ws + OFF_Y0);
    float* OP = (float*)(ws + OFF_OP);

    // zero barrier flags (ws is poisoned each call); OP fully overwritten before read
    hipMemsetAsync(ws + OFF_CTR, 0, 4096, stream);

    prep_kernel<<<13328, TPB, 0, stream>>>(c_star, init_h_w, init_c_w, W_hh0, W_hh1,
                                           b_ih0, b_hh0, b_ih1, b_hh1,
                                           csb, ihwb, icwb, whh0b, whh1b, gb0, gb1);
    pack_wih1_kernel<<<512, TPB, 0, stream>>>(W_ih1, wih1p);
    init_gemm_kernel<<<256, TPB, 0, stream>>>(csb, ihwb, icwb, init_h_b, init_c_b,
                                              hl0, hl1, cl0, cl1);

    const bf16_t* a_whh0 = whh0b; const bf16_t* a_whh1 = whh1b;
    const bf16_t* a_wih1p = wih1p; const float* a_gb0 = gb0; const float* a_gb1 = gb1;
    const float* a_outw = out_w;
    bf16_t* a_hl0 = hl0; bf16_t* a_hl1 = hl1;
    const float* a_cl0 = cl0; const float* a_cl1 = cl1;
    bf16_t* a_y0 = y0; float* a_OP = OP; unsigned* a_flg = flg;
    void* args[] = {&a_whh0, &a_whh1, &a_wih1p, &a_gb0, &a_gb1, &a_outw,
                    &a_hl0, &a_hl1, &a_cl0, &a_cl1, &a_y0, &a_OP, &a_flg};
    hipLaunchCooperativeKernel((void*)lstm_main_kernel, dim3(NB), dim3(TPBM), args, 0, stream);

    finalize_kernel<<<512, TPB, 0, stream>>>(OP, out_b, (float*)d_out);
}